// Round 5
// baseline (541.927 us; speedup 1.0000x reference)
//
#include <hip/hip_runtime.h>

typedef __bf16 bf16;
typedef __bf16 bf16x8 __attribute__((ext_vector_type(8)));
typedef __bf16 bf16x4 __attribute__((ext_vector_type(4)));
typedef float  f32x4  __attribute__((ext_vector_type(4)));
typedef float  f32x16 __attribute__((ext_vector_type(16)));
typedef unsigned int u32x4 __attribute__((ext_vector_type(4)));

#define MFMA16(a, b, c) __builtin_amdgcn_mfma_f32_16x16x32_bf16((a), (b), (c), 0, 0, 0)
#define MFMA32(a, b, c) __builtin_amdgcn_mfma_f32_32x32x16_bf16((a), (b), (c), 0, 0, 0)

// async global->LDS, 16B per lane, LDS dst = wave-uniform base + lane*16
__device__ __forceinline__ void gload_lds16(const bf16* g, bf16* l) {
  __builtin_amdgcn_global_load_lds(
      (const __attribute__((address_space(1))) void*)g,
      (__attribute__((address_space(3))) void*)l, 16, 0, 0);
}

// ---------------- prep kernels ----------------

__global__ __launch_bounds__(256) void cast_bf16_kernel(
    const float* __restrict__ in, bf16* __restrict__ out, int n4) {
  int i = blockIdx.x * 256 + threadIdx.x;
  if (i < n4) {
    float4 v = reinterpret_cast<const float4*>(in)[i];
    bf16x4 o;
    o[0] = (bf16)v.x; o[1] = (bf16)v.y; o[2] = (bf16)v.z; o[3] = (bf16)v.w;
    reinterpret_cast<bf16x4*>(out)[i] = o;
  }
}

__global__ __launch_bounds__(256) void transpose_cast_kernel(
    const float* __restrict__ W, bf16* __restrict__ Wt, int K, int N) {
  __shared__ bf16 tile[64 * 66];
  const int k0 = blockIdx.y * 64, n0 = blockIdx.x * 64;
  const int c = threadIdx.x & 63, rb = threadIdx.x >> 6;
#pragma unroll
  for (int p = 0; p < 16; ++p) {
    int r = p * 4 + rb;
    tile[c * 66 + r] = (bf16)W[(long)(k0 + r) * N + n0 + c];
  }
  __syncthreads();
#pragma unroll
  for (int p = 0; p < 16; ++p) {
    int r = p * 4 + rb;
    Wt[(long)(n0 + r) * K + k0 + c] = tile[r * 66 + c];
  }
}

// ---------------- GEMM: C(M,N) = A(M,K) @ Bt(N,K)^T, m97 structure ----------------
template <int EPI>
__global__ __launch_bounds__(256, 2) void gemm_bt(
    const bf16* __restrict__ A, const bf16* __restrict__ Bt,
    const float* __restrict__ bias, bf16* __restrict__ oQ,
    bf16* __restrict__ oK, bf16* __restrict__ oVT, float* __restrict__ oC,
    int K) {
  __shared__ bf16 As[128 * 64];
  __shared__ bf16 Bs[128 * 64];
  const int tid = threadIdx.x, lane = tid & 63, wid = tid >> 6;
  const int wr = wid >> 1, wc = wid & 1;
  const int brow = blockIdx.x * 128, bcol = blockIdx.y * 128;
  const int srow = lane >> 3, scol8 = (lane & 7) * 8;
  const int c15 = lane & 15, g = lane >> 4;

  f32x4 acc[4][4];
#pragma unroll
  for (int m = 0; m < 4; ++m)
#pragma unroll
    for (int n = 0; n < 4; ++n) acc[m][n] = f32x4{0.f, 0.f, 0.f, 0.f};

  const bf16* Ab = A + (long)brow * K + scol8;
  const bf16* Bb = Bt + (long)bcol * K + scol8;

  for (int k0 = 0; k0 < K; k0 += 64) {
#pragma unroll
    for (int i = 0; i < 4; ++i) {
      int c = wid * 4 + i;
      int row = c * 8 + srow;
      gload_lds16(Ab + (long)row * K + k0, &As[c * 512]);
    }
#pragma unroll
    for (int i = 0; i < 4; ++i) {
      int c = wid * 4 + i;
      int row = c * 8 + srow;
      gload_lds16(Bb + (long)row * K + k0, &Bs[c * 512]);
    }
    __syncthreads();
#pragma unroll
    for (int kk = 0; kk < 64; kk += 32) {
      bf16x8 a[4], b[4];
#pragma unroll
      for (int m = 0; m < 4; ++m)
        a[m] = *(const bf16x8*)&As[(wr * 64 + m * 16 + c15) * 64 + kk + g * 8];
#pragma unroll
      for (int n = 0; n < 4; ++n)
        b[n] = *(const bf16x8*)&Bs[(wc * 64 + n * 16 + c15) * 64 + kk + g * 8];
#pragma unroll
      for (int m = 0; m < 4; ++m)
#pragma unroll
        for (int n = 0; n < 4; ++n)
          acc[m][n] = MFMA16(a[m], b[n], acc[m][n]);
    }
    __syncthreads();
  }

#pragma unroll
  for (int n = 0; n < 4; ++n) {
    const int col = bcol + wc * 64 + n * 16 + c15;
    const float bv = bias[col];
    if (EPI == 0) {
      const int which = col >> 10, wi = col & 1023, h = wi >> 6, d = wi & 63;
      const float sc = (which == 0) ? 0.18033688011112042f : 1.0f;  // 0.125*log2(e)
#pragma unroll
      for (int m = 0; m < 4; ++m) {
        const int row0 = brow + wr * 64 + m * 16 + g * 4;
        const int bb = row0 >> 11, t0 = row0 & 2047;
        const long hb = bb * 16 + h;
        if (which == 2) {
          bf16x4 pv;
#pragma unroll
          for (int r = 0; r < 4; ++r) pv[r] = (bf16)(acc[m][n][r] + bv);
          *(bf16x4*)&oVT[(hb * 64 + d) * 2048 + t0] = pv;  // (b,h,d,t)
        } else {
          bf16* dst = ((which == 0) ? oQ : oK) + (hb * 2048 + t0) * 64 + d;
#pragma unroll
          for (int r = 0; r < 4; ++r)
            dst[(long)r * 64] = (bf16)((acc[m][n][r] + bv) * sc);
        }
      }
    } else {
#pragma unroll
      for (int m = 0; m < 4; ++m) {
        const long row = brow + wr * 64 + m * 16 + g * 4;
#pragma unroll
        for (int r = 0; r < 4; ++r) oC[(row + r) * 1024 + col] = acc[m][n][r] + bv;
      }
    }
  }
}

// ---------------- flash attention, intra-block KV split x4 -------------------
// 2048 blocks x 4 waves. All 4 waves share ONE 32-query group; wave w covers
// KV tiles {w, w+4, ..., w+28} (512 keys) with online softmax, producing a
// partial (m, l, O). Partials merge in LDS (fp32, exact). 8192 waves total
// -> 4 waves/SIMD (vs 2 before): occupancy was the round-4 limiter.
__global__ __launch_bounds__(256, 4) void attn_kernel(
    const bf16* __restrict__ Q, const bf16* __restrict__ K,
    const bf16* __restrict__ VT, const int* __restrict__ mask,
    bf16* __restrict__ Aout) {
  __shared__ float Ol[4][16][2][64];  // [wave][reg r][o0/o1][lane] partial O
  __shared__ float ml[4][2][32];      // [wave][{m,l}][query]
  __shared__ float sws[4][32];        // rare-path rescale broadcast
  const int tid = threadIdx.x, lane = tid & 63, w = tid >> 6;
  const int col = lane & 31, hi = lane >> 5;
  const int bid = blockIdx.x;
  const int swz = (bid & 7) * 256 + (bid >> 3);  // XCD swizzle: 4 bh per XCD
  const int qt = swz & 63, bh = swz >> 6;        // 64 q-groups of 32 per bh
  const int b = bh >> 4, h = bh & 15;
  const int q0 = qt * 32;

  // Q B-frag (pre-scaled by 0.125*log2e in gemm epilogue); same for all waves
  const bf16* Qp = Q + ((long)bh * 2048 + q0 + col) * 64 + hi * 8;
  bf16x8 bq[4];
#pragma unroll
  for (int dc = 0; dc < 4; ++dc) bq[dc] = *(const bf16x8*)(Qp + dc * 16);

  f32x16 o0, o1;
#pragma unroll
  for (int r = 0; r < 16; ++r) { o0[r] = 0.f; o1[r] = 0.f; }
  float mrun = -1e30f, lrun = 0.f;  // lrun = per-half partial until fold

  const bf16* Kbh = K + (long)bh * 2048 * 64;
  const bf16* Vbh = VT + (long)bh * 64 * 2048;
  const int* mb = mask + b * 2048;

  auto body = [&](const bf16x8* ak, bf16x8* akn, int t, int tn) {
    const int kbase = t * 64;
    // V loads for all 64 keys (consumed at PV, ~400 cy later)
    bf16x8 bv[8];
    {
      const bf16* Vp = Vbh + (long)col * 2048 + kbase + hi * 8;
#pragma unroll
      for (int s = 0; s < 4; ++s) {
        bv[s] = *(const bf16x8*)(Vp + s * 16);
        bv[4 + s] = *(const bf16x8*)(Vp + 32 * 2048 + s * 16);
      }
    }
    const int mvA = mb[kbase + col], mvB = mb[kbase + 32 + col];
    // S^T = K @ Q^T, two independent accumulator chains
    f32x16 stA, stB;
#pragma unroll
    for (int r = 0; r < 16; ++r) { stA[r] = 0.f; stB[r] = 0.f; }
    __builtin_amdgcn_s_setprio(1);
#pragma unroll
    for (int dc = 0; dc < 4; ++dc) stA = MFMA32(ak[dc], bq[dc], stA);
#pragma unroll
    for (int dc = 0; dc < 4; ++dc) stB = MFMA32(ak[4 + dc], bq[dc], stB);
    __builtin_amdgcn_s_setprio(0);
    // prefetch this wave's next K tile
    {
      const bf16* Kp = Kbh + (long)(tn * 64 + col) * 64 + hi * 8;
#pragma unroll
      for (int dc = 0; dc < 4; ++dc) {
        akn[dc] = *(const bf16x8*)(Kp + dc * 16);
        akn[4 + dc] = *(const bf16x8*)(Kp + 32 * 64 + dc * 16);
      }
    }
    // mask (wave-uniform skip when all-ones)
    unsigned kmA = (unsigned)__ballot(mvA != 0);
    unsigned kmB = (unsigned)__ballot(mvB != 0);
    if (kmA != 0xffffffffu) {
#pragma unroll
      for (int r = 0; r < 16; ++r)
        if (!((kmA >> ((r & 3) + 8 * (r >> 2) + 4 * hi)) & 1)) stA[r] = -1e30f;
    }
    if (kmB != 0xffffffffu) {
#pragma unroll
      for (int r = 0; r < 16; ++r)
        if (!((kmB >> ((r & 3) + 8 * (r >> 2) + 4 * hi)) & 1)) stB[r] = -1e30f;
    }
    // per-half max over this lane's 32 scores (no cross-half shuffle common path)
    float mx[8];
#pragma unroll
    for (int i = 0; i < 8; ++i)
      mx[i] = fmaxf(fmaxf(stA[2 * i], stA[2 * i + 1]),
                    fmaxf(stB[2 * i], stB[2 * i + 1]));
    float m0 = fmaxf(fmaxf(fmaxf(mx[0], mx[1]), fmaxf(mx[2], mx[3])),
                     fmaxf(fmaxf(mx[4], mx[5]), fmaxf(mx[6], mx[7])));
    // defer-max: rescale only when some row's max grew past THR=8 (log2 units)
    if (__any(m0 > mrun + 8.0f)) {
      float pm = fmaxf(m0, __shfl_xor(m0, 32));  // cross-half only on rare path
      float mnew = fmaxf(mrun, pm);
      float scale = __builtin_exp2f(mrun - mnew);
      mrun = mnew;
      lrun *= scale;
      if (hi == 0) sws[w][col] = scale;  // broadcast q-layout -> d-layout
      asm volatile("s_waitcnt lgkmcnt(0)" ::: "memory");
#pragma unroll
      for (int r = 0; r < 16; ++r) {
        float sc = sws[w][(r & 3) + 8 * (r >> 2) + 4 * hi];
        o0[r] *= sc; o1[r] *= sc;
      }
    }
    // P = exp2(S - m); per-half row-sum accumulates into lrun partial
    float pA[16], pB[16];
#pragma unroll
    for (int r = 0; r < 16; ++r) {
      pA[r] = __builtin_exp2f(stA[r] - mrun);
      pB[r] = __builtin_exp2f(stB[r] - mrun);
    }
    float sm[8];
#pragma unroll
    for (int i = 0; i < 8; ++i)
      sm[i] = (pA[2 * i] + pA[2 * i + 1]) + (pB[2 * i] + pB[2 * i + 1]);
    lrun += ((sm[0] + sm[1]) + (sm[2] + sm[3])) + ((sm[4] + sm[5]) + (sm[6] + sm[7]));
    // P -> bf16 A-frags; all 8 cross-half exchanges issued in one window
    unsigned dA[8], dB[8];
#pragma unroll
    for (int i = 0; i < 8; ++i) {
      union { bf16 h[2]; unsigned u; } ta, tb;
      ta.h[0] = (bf16)pA[2 * i]; ta.h[1] = (bf16)pA[2 * i + 1];
      tb.h[0] = (bf16)pB[2 * i]; tb.h[1] = (bf16)pB[2 * i + 1];
      dA[i] = ta.u; dB[i] = tb.u;
    }
    unsigned gA02 = (unsigned)__shfl_xor((int)(hi ? dA[0] : dA[2]), 32);
    unsigned gA13 = (unsigned)__shfl_xor((int)(hi ? dA[1] : dA[3]), 32);
    unsigned gA46 = (unsigned)__shfl_xor((int)(hi ? dA[4] : dA[6]), 32);
    unsigned gA57 = (unsigned)__shfl_xor((int)(hi ? dA[5] : dA[7]), 32);
    unsigned gB02 = (unsigned)__shfl_xor((int)(hi ? dB[0] : dB[2]), 32);
    unsigned gB13 = (unsigned)__shfl_xor((int)(hi ? dB[1] : dB[3]), 32);
    unsigned gB46 = (unsigned)__shfl_xor((int)(hi ? dB[4] : dB[6]), 32);
    unsigned gB57 = (unsigned)__shfl_xor((int)(hi ? dB[5] : dB[7]), 32);
    u32x4 wA0 = {hi ? gA02 : dA[0], hi ? gA13 : dA[1], hi ? dA[2] : gA02, hi ? dA[3] : gA13};
    u32x4 wA1 = {hi ? gA46 : dA[4], hi ? gA57 : dA[5], hi ? dA[6] : gA46, hi ? dA[7] : gA57};
    u32x4 wB0 = {hi ? gB02 : dB[0], hi ? gB13 : dB[1], hi ? dB[2] : gB02, hi ? dB[3] : gB13};
    u32x4 wB1 = {hi ? gB46 : dB[4], hi ? gB57 : dB[5], hi ? dB[6] : gB46, hi ? dB[7] : gB57};
    bf16x8 pa0 = __builtin_bit_cast(bf16x8, wA0);
    bf16x8 pa1 = __builtin_bit_cast(bf16x8, wA1);
    bf16x8 pa2 = __builtin_bit_cast(bf16x8, wB0);
    bf16x8 pa3 = __builtin_bit_cast(bf16x8, wB1);
    // O += P @ V (8 MFMAs, two independent accumulators)
    __builtin_amdgcn_s_setprio(1);
    o0 = MFMA32(pa0, bv[0], o0);
    o0 = MFMA32(pa1, bv[1], o0);
    o0 = MFMA32(pa2, bv[2], o0);
    o0 = MFMA32(pa3, bv[3], o0);
    o1 = MFMA32(pa0, bv[4], o1);
    o1 = MFMA32(pa1, bv[5], o1);
    o1 = MFMA32(pa2, bv[6], o1);
    o1 = MFMA32(pa3, bv[7], o1);
    __builtin_amdgcn_s_setprio(0);
  };

  // wave w's tiles: w, w+4, ..., w+28
  bf16x8 akA[8], akB[8];
  {
    const bf16* Kp = Kbh + (long)(w * 64 + col) * 64 + hi * 8;
#pragma unroll
    for (int dc = 0; dc < 4; ++dc) {
      akA[dc] = *(const bf16x8*)(Kp + dc * 16);
      akA[4 + dc] = *(const bf16x8*)(Kp + 32 * 64 + dc * 16);
    }
  }
  for (int j = 0; j < 8; j += 2) {
    const int t0 = w + 4 * j, t1 = w + 4 * (j + 1);
    const int t2 = (j + 2 < 8) ? w + 4 * (j + 2) : t1;
    body(akA, akB, t0, t1);
    body(akB, akA, t1, t2);
  }

  // ---- merge 4 KV-split partials in LDS ----
  lrun += __shfl_xor(lrun, 32);  // fold per-half l partials
  if (hi == 0) { ml[w][0][col] = mrun; ml[w][1][col] = lrun; }
#pragma unroll
  for (int r = 0; r < 16; ++r) {
    Ol[w][r][0][lane] = o0[r];
    Ol[w][r][1][lane] = o1[r];
  }
  __syncthreads();
  // wave w merges reg-block r in [4w, 4w+4); qr = rr + 8w + 4hi
#pragma unroll
  for (int rr = 0; rr < 4; ++rr) {
    const int r = w * 4 + rr;
    const int qr = rr + 8 * w + 4 * hi;
    float m0v = ml[0][0][qr], m1v = ml[1][0][qr];
    float m2v = ml[2][0][qr], m3v = ml[3][0][qr];
    float ms = fmaxf(fmaxf(m0v, m1v), fmaxf(m2v, m3v));
    float s0 = __builtin_exp2f(m0v - ms), s1 = __builtin_exp2f(m1v - ms);
    float s2 = __builtin_exp2f(m2v - ms), s3 = __builtin_exp2f(m3v - ms);
    float ls = ml[0][1][qr] * s0 + ml[1][1][qr] * s1 +
               ml[2][1][qr] * s2 + ml[3][1][qr] * s3;
    float inv = 1.0f / ls;
    float v0 = (Ol[0][r][0][lane] * s0 + Ol[1][r][0][lane] * s1 +
                Ol[2][r][0][lane] * s2 + Ol[3][r][0][lane] * s3) * inv;
    float v1 = (Ol[0][r][1][lane] * s0 + Ol[1][r][1][lane] * s1 +
                Ol[2][r][1][lane] * s2 + Ol[3][r][1][lane] * s3) * inv;
    long base = ((long)b * 2048 + q0 + qr) * 1024 + h * 64 + col;
    Aout[base] = (bf16)v0;
    Aout[base + 32] = (bf16)v1;
  }
}

// ---------------- launcher ----------------
extern "C" void kernel_launch(void* const* d_in, const int* in_sizes, int n_in,
                              void* d_out, int out_size, void* d_ws,
                              size_t ws_size, hipStream_t stream) {
  const float* x    = (const float*)d_in[0];
  const int*   mask = (const int*)d_in[1];
  const float* Wqkv = (const float*)d_in[2];
  const float* bqkv = (const float*)d_in[3];
  const float* Wout = (const float*)d_in[4];
  const float* bout = (const float*)d_in[5];
  float* out = (float*)d_out;

  char* ws = (char*)d_ws;
  bf16* xb    = (bf16*)(ws);                      // 8 MB
  bf16* wqkvT = (bf16*)(ws + (8u << 20));         // 6 MB
  bf16* woutT = (bf16*)(ws + (14u << 20));        // 2 MB
  bf16* Qb    = (bf16*)(ws + (16u << 20));        // 8 MB (b,h,t,d)
  bf16* Kb    = (bf16*)(ws + (24u << 20));        // 8 MB (b,h,t,d)
  bf16* VTb   = (bf16*)(ws + (32u << 20));        // 8 MB (b,h,d,t)
  bf16* Aatt  = xb;

  cast_bf16_kernel<<<4096, 256, 0, stream>>>(x, xb, (4096 * 1024) / 4);
  transpose_cast_kernel<<<dim3(48, 16), 256, 0, stream>>>(Wqkv, wqkvT, 1024, 3072);
  transpose_cast_kernel<<<dim3(16, 16), 256, 0, stream>>>(Wout, woutT, 1024, 1024);
  gemm_bt<0><<<dim3(32, 24), 256, 0, stream>>>(xb, wqkvT, bqkv, Qb, Kb, VTb,
                                               nullptr, 1024);
  attn_kernel<<<2048, 256, 0, stream>>>(Qb, Kb, VTb, mask, Aatt);
  gemm_bt<1><<<dim3(32, 8), 256, 0, stream>>>(Aatt, woutT, bout, nullptr,
                                              nullptr, nullptr, out, 1024);
}

// Round 6
// 458.179 us; speedup vs baseline: 1.1828x; 1.1828x over previous
//
#include <hip/hip_runtime.h>

typedef __bf16 bf16;
typedef __bf16 bf16x8 __attribute__((ext_vector_type(8)));
typedef __bf16 bf16x4 __attribute__((ext_vector_type(4)));
typedef float  f32x4  __attribute__((ext_vector_type(4)));
typedef float  f32x16 __attribute__((ext_vector_type(16)));
typedef unsigned int u32x4 __attribute__((ext_vector_type(4)));

#define MFMA16(a, b, c) __builtin_amdgcn_mfma_f32_16x16x32_bf16((a), (b), (c), 0, 0, 0)
#define MFMA32(a, b, c) __builtin_amdgcn_mfma_f32_32x32x16_bf16((a), (b), (c), 0, 0, 0)

// async global->LDS, 16B per lane, LDS dst = wave-uniform base + lane*16
__device__ __forceinline__ void gload_lds16(const bf16* g, bf16* l) {
  __builtin_amdgcn_global_load_lds(
      (const __attribute__((address_space(1))) void*)g,
      (__attribute__((address_space(3))) void*)l, 16, 0, 0);
}

// ---------------- prep kernels ----------------

__global__ __launch_bounds__(256) void cast_bf16_kernel(
    const float* __restrict__ in, bf16* __restrict__ out, int n4) {
  int i = blockIdx.x * 256 + threadIdx.x;
  if (i < n4) {
    float4 v = reinterpret_cast<const float4*>(in)[i];
    bf16x4 o;
    o[0] = (bf16)v.x; o[1] = (bf16)v.y; o[2] = (bf16)v.z; o[3] = (bf16)v.w;
    reinterpret_cast<bf16x4*>(out)[i] = o;
  }
}

__global__ __launch_bounds__(256) void transpose_cast_kernel(
    const float* __restrict__ W, bf16* __restrict__ Wt, int K, int N) {
  __shared__ bf16 tile[64 * 66];
  const int k0 = blockIdx.y * 64, n0 = blockIdx.x * 64;
  const int c = threadIdx.x & 63, rb = threadIdx.x >> 6;
#pragma unroll
  for (int p = 0; p < 16; ++p) {
    int r = p * 4 + rb;
    tile[c * 66 + r] = (bf16)W[(long)(k0 + r) * N + n0 + c];
  }
  __syncthreads();
#pragma unroll
  for (int p = 0; p < 16; ++p) {
    int r = p * 4 + rb;
    Wt[(long)(n0 + r) * K + k0 + c] = tile[r * 66 + c];
  }
}

// ---------------- GEMM: C(M,N) = A(M,K) @ Bt(N,K)^T, m97 structure ----------------
template <int EPI>
__global__ __launch_bounds__(256, 2) void gemm_bt(
    const bf16* __restrict__ A, const bf16* __restrict__ Bt,
    const float* __restrict__ bias, bf16* __restrict__ oQ,
    bf16* __restrict__ oK, bf16* __restrict__ oVT, float* __restrict__ oC,
    int K) {
  __shared__ bf16 As[128 * 64];
  __shared__ bf16 Bs[128 * 64];
  const int tid = threadIdx.x, lane = tid & 63, wid = tid >> 6;
  const int wr = wid >> 1, wc = wid & 1;
  const int brow = blockIdx.x * 128, bcol = blockIdx.y * 128;
  const int srow = lane >> 3, scol8 = (lane & 7) * 8;
  const int c15 = lane & 15, g = lane >> 4;

  f32x4 acc[4][4];
#pragma unroll
  for (int m = 0; m < 4; ++m)
#pragma unroll
    for (int n = 0; n < 4; ++n) acc[m][n] = f32x4{0.f, 0.f, 0.f, 0.f};

  const bf16* Ab = A + (long)brow * K + scol8;
  const bf16* Bb = Bt + (long)bcol * K + scol8;

  for (int k0 = 0; k0 < K; k0 += 64) {
#pragma unroll
    for (int i = 0; i < 4; ++i) {
      int c = wid * 4 + i;
      int row = c * 8 + srow;
      gload_lds16(Ab + (long)row * K + k0, &As[c * 512]);
    }
#pragma unroll
    for (int i = 0; i < 4; ++i) {
      int c = wid * 4 + i;
      int row = c * 8 + srow;
      gload_lds16(Bb + (long)row * K + k0, &Bs[c * 512]);
    }
    __syncthreads();
#pragma unroll
    for (int kk = 0; kk < 64; kk += 32) {
      bf16x8 a[4], b[4];
#pragma unroll
      for (int m = 0; m < 4; ++m)
        a[m] = *(const bf16x8*)&As[(wr * 64 + m * 16 + c15) * 64 + kk + g * 8];
#pragma unroll
      for (int n = 0; n < 4; ++n)
        b[n] = *(const bf16x8*)&Bs[(wc * 64 + n * 16 + c15) * 64 + kk + g * 8];
#pragma unroll
      for (int m = 0; m < 4; ++m)
#pragma unroll
        for (int n = 0; n < 4; ++n)
          acc[m][n] = MFMA16(a[m], b[n], acc[m][n]);
    }
    __syncthreads();
  }

#pragma unroll
  for (int n = 0; n < 4; ++n) {
    const int col = bcol + wc * 64 + n * 16 + c15;
    const float bv = bias[col];
    if (EPI == 0) {
      const int which = col >> 10, wi = col & 1023, h = wi >> 6, d = wi & 63;
      const float sc = (which == 0) ? 0.18033688011112042f : 1.0f;  // 0.125*log2(e)
#pragma unroll
      for (int m = 0; m < 4; ++m) {
        const int row0 = brow + wr * 64 + m * 16 + g * 4;
        const int bb = row0 >> 11, t0 = row0 & 2047;
        const long hb = bb * 16 + h;
        if (which == 2) {
          bf16x4 pv;
#pragma unroll
          for (int r = 0; r < 4; ++r) pv[r] = (bf16)(acc[m][n][r] + bv);
          *(bf16x4*)&oVT[(hb * 64 + d) * 2048 + t0] = pv;  // (b,h,d,t)
        } else {
          bf16* dst = ((which == 0) ? oQ : oK) + (hb * 2048 + t0) * 64 + d;
#pragma unroll
          for (int r = 0; r < 4; ++r)
            dst[(long)r * 64] = (bf16)((acc[m][n][r] + bv) * sc);
        }
      }
    } else {
#pragma unroll
      for (int m = 0; m < 4; ++m) {
        const long row = brow + wr * 64 + m * 16 + g * 4;
#pragma unroll
        for (int r = 0; r < 4; ++r) oC[(row + r) * 1024 + col] = acc[m][n][r] + bv;
      }
    }
  }
}

// ---------------- flash attention: KV-split x4, round-3 body (VGPR~80) -------
// 2048 blocks x 4 waves sharing ONE 32-query group. Wave w covers 16 tiles of
// 32 keys {w, w+4, ..., w+60/..}: online softmax -> partial (m,l,O); partials
// merged in LDS (fp32, exact). Body is the round-3 one (32 keys/iter,
// K ping-pong, early V): measured VGPR=80 -> fits the 128-reg 4-wave/SIMD
// quantum WITHOUT spills (round-5 spilled: 1.39 GB scratch writes).
__global__ __launch_bounds__(256, 4) void attn_kernel(
    const bf16* __restrict__ Q, const bf16* __restrict__ K,
    const bf16* __restrict__ VT, const int* __restrict__ mask,
    bf16* __restrict__ Aout) {
  __shared__ float Ol[4][16][2][64];  // [wave][reg r][o0/o1][lane] partial O
  __shared__ float ml[4][2][32];      // [wave][{m,l}][query]
  __shared__ float sws[4][32];        // rare-path rescale broadcast
  const int tid = threadIdx.x, lane = tid & 63, w = tid >> 6;
  const int col = lane & 31, hi = lane >> 5;
  const int bid = blockIdx.x;
  const int swz = (bid & 7) * 256 + (bid >> 3);  // XCD swizzle
  const int qt = swz & 63, bh = swz >> 6;        // 64 q-groups of 32 per bh
  const int b = bh >> 4, h = bh & 15;
  const int q0 = qt * 32;

  // Q B-frag (pre-scaled by 0.125*log2e in gemm epilogue); same for all waves
  const bf16* Qp = Q + ((long)bh * 2048 + q0 + col) * 64 + hi * 8;
  bf16x8 bq[4];
#pragma unroll
  for (int dc = 0; dc < 4; ++dc) bq[dc] = *(const bf16x8*)(Qp + dc * 16);

  f32x16 o0, o1;
#pragma unroll
  for (int r = 0; r < 16; ++r) { o0[r] = 0.f; o1[r] = 0.f; }
  float mrun = -1e30f, lrun = 0.f;  // lrun = per-half partial until fold

  const bf16* Kbh = K + (long)bh * 2048 * 64;
  const bf16* Vbh = VT + (long)bh * 64 * 2048;
  const int* mb = mask + b * 2048;

  auto body = [&](const bf16x8* ak, bf16x8* akn, int t, int tn) {
    const int kbase = t * 32;
    // V loads early (consumed ~300 cy later by PV)
    bf16x8 bv00, bv01, bv10, bv11;
    {
      const bf16* Vp = Vbh + (long)col * 2048 + kbase + hi * 8;
      bv00 = *(const bf16x8*)(Vp);
      bv10 = *(const bf16x8*)(Vp + 16);
      bv01 = *(const bf16x8*)(Vp + 32 * 2048);
      bv11 = *(const bf16x8*)(Vp + 32 * 2048 + 16);
    }
    // S^T = K @ Q^T
    f32x16 st;
#pragma unroll
    for (int r = 0; r < 16; ++r) st[r] = 0.f;
    __builtin_amdgcn_s_setprio(1);
#pragma unroll
    for (int dc = 0; dc < 4; ++dc) st = MFMA32(ak[dc], bq[dc], st);
    __builtin_amdgcn_s_setprio(0);
    // prefetch this wave's next K tile into the other buffer
    {
      const bf16* Kp = Kbh + (long)(tn * 32 + col) * 64 + hi * 8;
#pragma unroll
      for (int dc = 0; dc < 4; ++dc) akn[dc] = *(const bf16x8*)(Kp + dc * 16);
    }
    // mask (wave-uniform skip when all-ones)
    unsigned km32 = (unsigned)__ballot(mb[kbase + col] != 0);
    if (km32 != 0xffffffffu) {
      unsigned km = km32 >> (hi * 4);
#pragma unroll
      for (int r = 0; r < 16; ++r)
        if (!((km >> ((r & 3) + 8 * (r >> 2))) & 1)) st[r] = -1e30f;
    }
    // per-half row max (cross-half shuffle only on rare rescale path)
    float m01 = fmaxf(st[0], st[1]), m23 = fmaxf(st[2], st[3]);
    float m45 = fmaxf(st[4], st[5]), m67 = fmaxf(st[6], st[7]);
    float m89 = fmaxf(st[8], st[9]), mab = fmaxf(st[10], st[11]);
    float mcd = fmaxf(st[12], st[13]), mef = fmaxf(st[14], st[15]);
    float m0 = fmaxf(fmaxf(fmaxf(m01, m23), fmaxf(m45, m67)),
                     fmaxf(fmaxf(m89, mab), fmaxf(mcd, mef)));
    // defer-max: rescale only when some row's max grew past THR=8 (log2 units)
    if (__any(m0 > mrun + 8.0f)) {
      float pm = fmaxf(m0, __shfl_xor(m0, 32));
      float mnew = fmaxf(mrun, pm);
      float scale = __builtin_exp2f(mrun - mnew);
      mrun = mnew;
      lrun *= scale;
      if (hi == 0) sws[w][col] = scale;  // broadcast q-layout -> d-layout
      asm volatile("s_waitcnt lgkmcnt(0)" ::: "memory");
#pragma unroll
      for (int r = 0; r < 16; ++r) {
        float sc = sws[w][(r & 3) + 8 * (r >> 2) + 4 * hi];
        o0[r] *= sc; o1[r] *= sc;
      }
    }
    // P = exp2(S - m); per-half row-sum accumulates into lrun partial
    float p[16];
#pragma unroll
    for (int r = 0; r < 16; ++r) p[r] = __builtin_exp2f(st[r] - mrun);
    float s01 = p[0] + p[1], s23 = p[2] + p[3], s45 = p[4] + p[5];
    float s67 = p[6] + p[7], s89 = p[8] + p[9], sab = p[10] + p[11];
    float scd = p[12] + p[13], sef = p[14] + p[15];
    lrun += ((s01 + s23) + (s45 + s67)) + ((s89 + sab) + (scd + sef));
    // P -> bf16 A-frags; 4 cross-half exchanges issued in one window
    unsigned d[8];
#pragma unroll
    for (int i = 0; i < 8; ++i) {
      union { bf16 h[2]; unsigned u; } tt;
      tt.h[0] = (bf16)p[2 * i]; tt.h[1] = (bf16)p[2 * i + 1];
      d[i] = tt.u;
    }
    unsigned g02 = (unsigned)__shfl_xor((int)(hi ? d[0] : d[2]), 32);
    unsigned g13 = (unsigned)__shfl_xor((int)(hi ? d[1] : d[3]), 32);
    unsigned g46 = (unsigned)__shfl_xor((int)(hi ? d[4] : d[6]), 32);
    unsigned g57 = (unsigned)__shfl_xor((int)(hi ? d[5] : d[7]), 32);
    u32x4 w0 = {hi ? g02 : d[0], hi ? g13 : d[1], hi ? d[2] : g02, hi ? d[3] : g13};
    u32x4 w1 = {hi ? g46 : d[4], hi ? g57 : d[5], hi ? d[6] : g46, hi ? d[7] : g57};
    bf16x8 pa0 = __builtin_bit_cast(bf16x8, w0);
    bf16x8 pa1 = __builtin_bit_cast(bf16x8, w1);
    // O += P @ V
    __builtin_amdgcn_s_setprio(1);
    o0 = MFMA32(pa0, bv00, o0);
    o0 = MFMA32(pa1, bv10, o0);
    o1 = MFMA32(pa0, bv01, o1);
    o1 = MFMA32(pa1, bv11, o1);
    __builtin_amdgcn_s_setprio(0);
  };

  // wave w's tiles: w, w+4, ..., w+60 (16 tiles of 32 keys)
  bf16x8 akA[4], akB[4];
  {
    const bf16* Kp = Kbh + (long)(w * 32 + col) * 64 + hi * 8;
#pragma unroll
    for (int dc = 0; dc < 4; ++dc) akA[dc] = *(const bf16x8*)(Kp + dc * 16);
  }
  for (int j = 0; j < 16; j += 2) {
    const int t0 = w + 4 * j, t1 = w + 4 * (j + 1);
    const int t2 = (j + 2 < 16) ? w + 4 * (j + 2) : t1;
    body(akA, akB, t0, t1);
    body(akB, akA, t1, t2);
  }

  // ---- merge 4 KV-split partials in LDS ----
  lrun += __shfl_xor(lrun, 32);  // fold per-half l partials
  if (hi == 0) { ml[w][0][col] = mrun; ml[w][1][col] = lrun; }
#pragma unroll
  for (int r = 0; r < 16; ++r) {
    Ol[w][r][0][lane] = o0[r];
    Ol[w][r][1][lane] = o1[r];
  }
  __syncthreads();
  // wave w merges reg-block r in [4w, 4w+4); qr = rr + 8w + 4hi
#pragma unroll
  for (int rr = 0; rr < 4; ++rr) {
    const int r = w * 4 + rr;
    const int qr = rr + 8 * w + 4 * hi;
    float m0v = ml[0][0][qr], m1v = ml[1][0][qr];
    float m2v = ml[2][0][qr], m3v = ml[3][0][qr];
    float ms = fmaxf(fmaxf(m0v, m1v), fmaxf(m2v, m3v));
    float s0 = __builtin_exp2f(m0v - ms), s1 = __builtin_exp2f(m1v - ms);
    float s2 = __builtin_exp2f(m2v - ms), s3 = __builtin_exp2f(m3v - ms);
    float ls = ml[0][1][qr] * s0 + ml[1][1][qr] * s1 +
               ml[2][1][qr] * s2 + ml[3][1][qr] * s3;
    float inv = 1.0f / ls;
    float v0 = (Ol[0][r][0][lane] * s0 + Ol[1][r][0][lane] * s1 +
                Ol[2][r][0][lane] * s2 + Ol[3][r][0][lane] * s3) * inv;
    float v1 = (Ol[0][r][1][lane] * s0 + Ol[1][r][1][lane] * s1 +
                Ol[2][r][1][lane] * s2 + Ol[3][r][1][lane] * s3) * inv;
    long base = ((long)b * 2048 + q0 + qr) * 1024 + h * 64 + col;
    Aout[base] = (bf16)v0;
    Aout[base + 32] = (bf16)v1;
  }
}

// ---------------- launcher ----------------
extern "C" void kernel_launch(void* const* d_in, const int* in_sizes, int n_in,
                              void* d_out, int out_size, void* d_ws,
                              size_t ws_size, hipStream_t stream) {
  const float* x    = (const float*)d_in[0];
  const int*   mask = (const int*)d_in[1];
  const float* Wqkv = (const float*)d_in[2];
  const float* bqkv = (const float*)d_in[3];
  const float* Wout = (const float*)d_in[4];
  const float* bout = (const float*)d_in[5];
  float* out = (float*)d_out;

  char* ws = (char*)d_ws;
  bf16* xb    = (bf16*)(ws);                      // 8 MB
  bf16* wqkvT = (bf16*)(ws + (8u << 20));         // 6 MB
  bf16* woutT = (bf16*)(ws + (14u << 20));        // 2 MB
  bf16* Qb    = (bf16*)(ws + (16u << 20));        // 8 MB (b,h,t,d)
  bf16* Kb    = (bf16*)(ws + (24u << 20));        // 8 MB (b,h,t,d)
  bf16* VTb   = (bf16*)(ws + (32u << 20));        // 8 MB (b,h,d,t)
  bf16* Aatt  = xb;

  cast_bf16_kernel<<<4096, 256, 0, stream>>>(x, xb, (4096 * 1024) / 4);
  transpose_cast_kernel<<<dim3(48, 16), 256, 0, stream>>>(Wqkv, wqkvT, 1024, 3072);
  transpose_cast_kernel<<<dim3(16, 16), 256, 0, stream>>>(Wout, woutT, 1024, 1024);
  gemm_bt<0><<<dim3(32, 24), 256, 0, stream>>>(xb, wqkvT, bqkv, Qb, Kb, VTb,
                                               nullptr, 1024);
  attn_kernel<<<2048, 256, 0, stream>>>(Qb, Kb, VTb, mask, Aatt);
  gemm_bt<1><<<dim3(32, 8), 256, 0, stream>>>(Aatt, woutT, bout, nullptr,
                                              nullptr, nullptr, out, 1024);
}

// Round 7
// 246.570 us; speedup vs baseline: 2.1979x; 1.8582x over previous
//
#include <hip/hip_runtime.h>

typedef __bf16 bf16;
typedef __bf16 bf16x8 __attribute__((ext_vector_type(8)));
typedef __bf16 bf16x4 __attribute__((ext_vector_type(4)));
typedef float  f32x4  __attribute__((ext_vector_type(4)));
typedef float  f32x16 __attribute__((ext_vector_type(16)));
typedef unsigned int u32x4 __attribute__((ext_vector_type(4)));

#define MFMA16(a, b, c) __builtin_amdgcn_mfma_f32_16x16x32_bf16((a), (b), (c), 0, 0, 0)
#define MFMA32(a, b, c) __builtin_amdgcn_mfma_f32_32x32x16_bf16((a), (b), (c), 0, 0, 0)

// async global->LDS, 16B per lane, LDS dst = wave-uniform base + lane*16
__device__ __forceinline__ void gload_lds16(const bf16* g, bf16* l) {
  __builtin_amdgcn_global_load_lds(
      (const __attribute__((address_space(1))) void*)g,
      (__attribute__((address_space(3))) void*)l, 16, 0, 0);
}

// ---------------- prep kernels ----------------

__global__ __launch_bounds__(256) void cast_bf16_kernel(
    const float* __restrict__ in, bf16* __restrict__ out, int n4) {
  int i = blockIdx.x * 256 + threadIdx.x;
  if (i < n4) {
    float4 v = reinterpret_cast<const float4*>(in)[i];
    bf16x4 o;
    o[0] = (bf16)v.x; o[1] = (bf16)v.y; o[2] = (bf16)v.z; o[3] = (bf16)v.w;
    reinterpret_cast<bf16x4*>(out)[i] = o;
  }
}

__global__ __launch_bounds__(256) void transpose_cast_kernel(
    const float* __restrict__ W, bf16* __restrict__ Wt, int K, int N) {
  __shared__ bf16 tile[64 * 66];
  const int k0 = blockIdx.y * 64, n0 = blockIdx.x * 64;
  const int c = threadIdx.x & 63, rb = threadIdx.x >> 6;
#pragma unroll
  for (int p = 0; p < 16; ++p) {
    int r = p * 4 + rb;
    tile[c * 66 + r] = (bf16)W[(long)(k0 + r) * N + n0 + c];
  }
  __syncthreads();
#pragma unroll
  for (int p = 0; p < 16; ++p) {
    int r = p * 4 + rb;
    Wt[(long)(n0 + r) * K + k0 + c] = tile[r * 66 + c];
  }
}

// ---------------- GEMM: C(M,N) = A(M,K) @ Bt(N,K)^T, m97 structure ----------------
template <int EPI>
__global__ __launch_bounds__(256, 2) void gemm_bt(
    const bf16* __restrict__ A, const bf16* __restrict__ Bt,
    const float* __restrict__ bias, bf16* __restrict__ oQ,
    bf16* __restrict__ oK, bf16* __restrict__ oVT, float* __restrict__ oC,
    int K) {
  __shared__ bf16 As[128 * 64];
  __shared__ bf16 Bs[128 * 64];
  const int tid = threadIdx.x, lane = tid & 63, wid = tid >> 6;
  const int wr = wid >> 1, wc = wid & 1;
  const int brow = blockIdx.x * 128, bcol = blockIdx.y * 128;
  const int srow = lane >> 3, scol8 = (lane & 7) * 8;
  const int c15 = lane & 15, g = lane >> 4;

  f32x4 acc[4][4];
#pragma unroll
  for (int m = 0; m < 4; ++m)
#pragma unroll
    for (int n = 0; n < 4; ++n) acc[m][n] = f32x4{0.f, 0.f, 0.f, 0.f};

  const bf16* Ab = A + (long)brow * K + scol8;
  const bf16* Bb = Bt + (long)bcol * K + scol8;

  for (int k0 = 0; k0 < K; k0 += 64) {
#pragma unroll
    for (int i = 0; i < 4; ++i) {
      int c = wid * 4 + i;
      int row = c * 8 + srow;
      gload_lds16(Ab + (long)row * K + k0, &As[c * 512]);
    }
#pragma unroll
    for (int i = 0; i < 4; ++i) {
      int c = wid * 4 + i;
      int row = c * 8 + srow;
      gload_lds16(Bb + (long)row * K + k0, &Bs[c * 512]);
    }
    __syncthreads();
#pragma unroll
    for (int kk = 0; kk < 64; kk += 32) {
      bf16x8 a[4], b[4];
#pragma unroll
      for (int m = 0; m < 4; ++m)
        a[m] = *(const bf16x8*)&As[(wr * 64 + m * 16 + c15) * 64 + kk + g * 8];
#pragma unroll
      for (int n = 0; n < 4; ++n)
        b[n] = *(const bf16x8*)&Bs[(wc * 64 + n * 16 + c15) * 64 + kk + g * 8];
#pragma unroll
      for (int m = 0; m < 4; ++m)
#pragma unroll
        for (int n = 0; n < 4; ++n)
          acc[m][n] = MFMA16(a[m], b[n], acc[m][n]);
    }
    __syncthreads();
  }

#pragma unroll
  for (int n = 0; n < 4; ++n) {
    const int col = bcol + wc * 64 + n * 16 + c15;
    const float bv = bias[col];
    if (EPI == 0) {
      const int which = col >> 10, wi = col & 1023, h = wi >> 6, d = wi & 63;
      const float sc = (which == 0) ? 0.18033688011112042f : 1.0f;  // 0.125*log2(e)
#pragma unroll
      for (int m = 0; m < 4; ++m) {
        const int row0 = brow + wr * 64 + m * 16 + g * 4;
        const int bb = row0 >> 11, t0 = row0 & 2047;
        const long hb = bb * 16 + h;
        if (which == 2) {
          bf16x4 pv;
#pragma unroll
          for (int r = 0; r < 4; ++r) pv[r] = (bf16)(acc[m][n][r] + bv);
          *(bf16x4*)&oVT[(hb * 64 + d) * 2048 + t0] = pv;  // (b,h,d,t)
        } else {
          bf16* dst = ((which == 0) ? oQ : oK) + (hb * 2048 + t0) * 64 + d;
#pragma unroll
          for (int r = 0; r < 4; ++r)
            dst[(long)r * 64] = (bf16)((acc[m][n][r] + bv) * sc);
        }
      }
    } else {
#pragma unroll
      for (int m = 0; m < 4; ++m) {
        const long row = brow + wr * 64 + m * 16 + g * 4;
#pragma unroll
        for (int r = 0; r < 4; ++r) oC[(row + r) * 1024 + col] = acc[m][n][r] + bv;
      }
    }
  }
}

// ---------------- flash attention: KV-split x4, LEAN body (fits 128 regs) ----
// 2048 blocks x 4 waves sharing ONE 32-query group. Wave w covers 16 tiles of
// 32 keys {w, w+4, ...}: online softmax -> partial (m,l,O); merge in LDS.
// Round-6 lesson: at 4 waves/SIMD the budget is 128 unified regs/lane; the
// K ping-pong (+32 regs) forced spills (832 MB scratch writes). This body is
// single-buffered, just-in-time loads (mask -> K -> V issue order so the
// QK^T wait leaves V in flight); TLP from 4 waves/SIMD hides latency.
__global__ __launch_bounds__(256, 4) void attn_kernel(
    const bf16* __restrict__ Q, const bf16* __restrict__ K,
    const bf16* __restrict__ VT, const int* __restrict__ mask,
    bf16* __restrict__ Aout) {
  __shared__ float Ol[4][16][2][64];  // [wave][reg r][o0/o1][lane] partial O
  __shared__ float ml[4][2][32];      // [wave][{m,l}][query]
  __shared__ float sws[4][32];        // rare-path rescale broadcast
  const int tid = threadIdx.x, lane = tid & 63, w = tid >> 6;
  const int col = lane & 31, hi = lane >> 5;
  const int bid = blockIdx.x;
  const int swz = (bid & 7) * 256 + (bid >> 3);  // XCD swizzle: 4 bh per XCD
  const int qt = swz & 63, bh = swz >> 6;        // 64 q-groups of 32 per bh
  const int b = bh >> 4, h = bh & 15;
  const int q0 = qt * 32;

  // Q B-frag (pre-scaled by 0.125*log2e in gemm epilogue); same for all waves
  const bf16* Qp = Q + ((long)bh * 2048 + q0 + col) * 64 + hi * 8;
  bf16x8 bq[4];
#pragma unroll
  for (int dc = 0; dc < 4; ++dc) bq[dc] = *(const bf16x8*)(Qp + dc * 16);

  f32x16 o0, o1;
#pragma unroll
  for (int r = 0; r < 16; ++r) { o0[r] = 0.f; o1[r] = 0.f; }
  float mrun = -1e30f, lrun = 0.f;  // lrun = per-half partial until fold

  const bf16* Kbh = K + (long)bh * 2048 * 64;
  const bf16* Vbh = VT + (long)bh * 64 * 2048;
  const int* mb = mask + b * 2048;

  for (int j = 0; j < 16; ++j) {
    const int t = w + 4 * j;
    const int kbase = t * 32;
    // issue order: mask -> K -> V (oldest-first vmcnt: QK^T's wait on K
    // leaves V outstanding; mask's use doesn't drain K/V)
    const int mv = mb[kbase + col];
    const bf16* Kp = Kbh + (long)(kbase + col) * 64 + hi * 8;
    bf16x8 ak0 = *(const bf16x8*)(Kp);
    bf16x8 ak1 = *(const bf16x8*)(Kp + 16);
    bf16x8 ak2 = *(const bf16x8*)(Kp + 32);
    bf16x8 ak3 = *(const bf16x8*)(Kp + 48);
    const bf16* Vp = Vbh + (long)col * 2048 + kbase + hi * 8;
    bf16x8 bv00 = *(const bf16x8*)(Vp);
    bf16x8 bv10 = *(const bf16x8*)(Vp + 16);
    bf16x8 bv01 = *(const bf16x8*)(Vp + 32 * 2048);
    bf16x8 bv11 = *(const bf16x8*)(Vp + 32 * 2048 + 16);
    // S^T = K @ Q^T
    f32x16 st;
#pragma unroll
    for (int r = 0; r < 16; ++r) st[r] = 0.f;
    __builtin_amdgcn_s_setprio(1);
    st = MFMA32(ak0, bq[0], st);
    st = MFMA32(ak1, bq[1], st);
    st = MFMA32(ak2, bq[2], st);
    st = MFMA32(ak3, bq[3], st);
    __builtin_amdgcn_s_setprio(0);
    // mask (wave-uniform skip when all-ones)
    unsigned km32 = (unsigned)__ballot(mv != 0);
    if (km32 != 0xffffffffu) {
      unsigned km = km32 >> (hi * 4);
#pragma unroll
      for (int r = 0; r < 16; ++r)
        if (!((km >> ((r & 3) + 8 * (r >> 2))) & 1)) st[r] = -1e30f;
    }
    // per-half row max (cross-half shuffle only on rare rescale path)
    float m01 = fmaxf(st[0], st[1]), m23 = fmaxf(st[2], st[3]);
    float m45 = fmaxf(st[4], st[5]), m67 = fmaxf(st[6], st[7]);
    float m89 = fmaxf(st[8], st[9]), mab = fmaxf(st[10], st[11]);
    float mcd = fmaxf(st[12], st[13]), mef = fmaxf(st[14], st[15]);
    float m0 = fmaxf(fmaxf(fmaxf(m01, m23), fmaxf(m45, m67)),
                     fmaxf(fmaxf(m89, mab), fmaxf(mcd, mef)));
    // defer-max: rescale only when some row's max grew past THR=8 (log2 units)
    if (__any(m0 > mrun + 8.0f)) {
      float pm = fmaxf(m0, __shfl_xor(m0, 32));
      float mnew = fmaxf(mrun, pm);
      float scale = __builtin_exp2f(mrun - mnew);
      mrun = mnew;
      lrun *= scale;
      if (hi == 0) sws[w][col] = scale;  // broadcast q-layout -> d-layout
      asm volatile("s_waitcnt lgkmcnt(0)" ::: "memory");
#pragma unroll
      for (int r = 0; r < 16; ++r) {
        float sc = sws[w][(r & 3) + 8 * (r >> 2) + 4 * hi];
        o0[r] *= sc; o1[r] *= sc;
      }
    }
    // P = exp2(S - m); per-half row-sum accumulates into lrun partial
    float p[16];
#pragma unroll
    for (int r = 0; r < 16; ++r) p[r] = __builtin_exp2f(st[r] - mrun);
    float s01 = p[0] + p[1], s23 = p[2] + p[3], s45 = p[4] + p[5];
    float s67 = p[6] + p[7], s89 = p[8] + p[9], sab = p[10] + p[11];
    float scd = p[12] + p[13], sef = p[14] + p[15];
    lrun += ((s01 + s23) + (s45 + s67)) + ((s89 + sab) + (scd + sef));
    // P -> bf16 A-frags; 4 cross-half exchanges issued in one window
    unsigned d0, d1, d2, d3, d4, d5, d6, d7;
    {
      union { bf16 hh[2]; unsigned u; } tt;
      tt.hh[0] = (bf16)p[0];  tt.hh[1] = (bf16)p[1];  d0 = tt.u;
      tt.hh[0] = (bf16)p[2];  tt.hh[1] = (bf16)p[3];  d1 = tt.u;
      tt.hh[0] = (bf16)p[4];  tt.hh[1] = (bf16)p[5];  d2 = tt.u;
      tt.hh[0] = (bf16)p[6];  tt.hh[1] = (bf16)p[7];  d3 = tt.u;
      tt.hh[0] = (bf16)p[8];  tt.hh[1] = (bf16)p[9];  d4 = tt.u;
      tt.hh[0] = (bf16)p[10]; tt.hh[1] = (bf16)p[11]; d5 = tt.u;
      tt.hh[0] = (bf16)p[12]; tt.hh[1] = (bf16)p[13]; d6 = tt.u;
      tt.hh[0] = (bf16)p[14]; tt.hh[1] = (bf16)p[15]; d7 = tt.u;
    }
    unsigned g02 = (unsigned)__shfl_xor((int)(hi ? d0 : d2), 32);
    unsigned g13 = (unsigned)__shfl_xor((int)(hi ? d1 : d3), 32);
    unsigned g46 = (unsigned)__shfl_xor((int)(hi ? d4 : d6), 32);
    unsigned g57 = (unsigned)__shfl_xor((int)(hi ? d5 : d7), 32);
    u32x4 w0 = {hi ? g02 : d0, hi ? g13 : d1, hi ? d2 : g02, hi ? d3 : g13};
    u32x4 w1 = {hi ? g46 : d4, hi ? g57 : d5, hi ? d6 : g46, hi ? d7 : g57};
    bf16x8 pa0 = __builtin_bit_cast(bf16x8, w0);
    bf16x8 pa1 = __builtin_bit_cast(bf16x8, w1);
    // O += P @ V
    __builtin_amdgcn_s_setprio(1);
    o0 = MFMA32(pa0, bv00, o0);
    o0 = MFMA32(pa1, bv10, o0);
    o1 = MFMA32(pa0, bv01, o1);
    o1 = MFMA32(pa1, bv11, o1);
    __builtin_amdgcn_s_setprio(0);
  }

  // ---- merge 4 KV-split partials in LDS ----
  lrun += __shfl_xor(lrun, 32);  // fold per-half l partials
  if (hi == 0) { ml[w][0][col] = mrun; ml[w][1][col] = lrun; }
#pragma unroll
  for (int r = 0; r < 16; ++r) {
    Ol[w][r][0][lane] = o0[r];
    Ol[w][r][1][lane] = o1[r];
  }
  __syncthreads();
  // wave w merges reg-block r in [4w, 4w+4); qr = rr + 8w + 4hi
#pragma unroll
  for (int rr = 0; rr < 4; ++rr) {
    const int r = w * 4 + rr;
    const int qr = rr + 8 * w + 4 * hi;
    float m0v = ml[0][0][qr], m1v = ml[1][0][qr];
    float m2v = ml[2][0][qr], m3v = ml[3][0][qr];
    float ms = fmaxf(fmaxf(m0v, m1v), fmaxf(m2v, m3v));
    float s0 = __builtin_exp2f(m0v - ms), s1 = __builtin_exp2f(m1v - ms);
    float s2 = __builtin_exp2f(m2v - ms), s3 = __builtin_exp2f(m3v - ms);
    float ls = ml[0][1][qr] * s0 + ml[1][1][qr] * s1 +
               ml[2][1][qr] * s2 + ml[3][1][qr] * s3;
    float inv = 1.0f / ls;
    float v0 = (Ol[0][r][0][lane] * s0 + Ol[1][r][0][lane] * s1 +
                Ol[2][r][0][lane] * s2 + Ol[3][r][0][lane] * s3) * inv;
    float v1 = (Ol[0][r][1][lane] * s0 + Ol[1][r][1][lane] * s1 +
                Ol[2][r][1][lane] * s2 + Ol[3][r][1][lane] * s3) * inv;
    long base = ((long)b * 2048 + q0 + qr) * 1024 + h * 64 + col;
    Aout[base] = (bf16)v0;
    Aout[base + 32] = (bf16)v1;
  }
}

// ---------------- launcher ----------------
extern "C" void kernel_launch(void* const* d_in, const int* in_sizes, int n_in,
                              void* d_out, int out_size, void* d_ws,
                              size_t ws_size, hipStream_t stream) {
  const float* x    = (const float*)d_in[0];
  const int*   mask = (const int*)d_in[1];
  const float* Wqkv = (const float*)d_in[2];
  const float* bqkv = (const float*)d_in[3];
  const float* Wout = (const float*)d_in[4];
  const float* bout = (const float*)d_in[5];
  float* out = (float*)d_out;

  char* ws = (char*)d_ws;
  bf16* xb    = (bf16*)(ws);                      // 8 MB
  bf16* wqkvT = (bf16*)(ws + (8u << 20));         // 6 MB
  bf16* woutT = (bf16*)(ws + (14u << 20));        // 2 MB
  bf16* Qb    = (bf16*)(ws + (16u << 20));        // 8 MB (b,h,t,d)
  bf16* Kb    = (bf16*)(ws + (24u << 20));        // 8 MB (b,h,t,d)
  bf16* VTb   = (bf16*)(ws + (32u << 20));        // 8 MB (b,h,d,t)
  bf16* Aatt  = xb;

  cast_bf16_kernel<<<4096, 256, 0, stream>>>(x, xb, (4096 * 1024) / 4);
  transpose_cast_kernel<<<dim3(48, 16), 256, 0, stream>>>(Wqkv, wqkvT, 1024, 3072);
  transpose_cast_kernel<<<dim3(16, 16), 256, 0, stream>>>(Wout, woutT, 1024, 1024);
  gemm_bt<0><<<dim3(32, 24), 256, 0, stream>>>(xb, wqkvT, bqkv, Qb, Kb, VTb,
                                               nullptr, 1024);
  attn_kernel<<<2048, 256, 0, stream>>>(Qb, Kb, VTb, mask, Aatt);
  gemm_bt<1><<<dim3(32, 8), 256, 0, stream>>>(Aatt, woutT, bout, nullptr,
                                              nullptr, nullptr, out, 1024);
}

// Round 8
// 178.512 us; speedup vs baseline: 3.0358x; 1.3813x over previous
//
#include <hip/hip_runtime.h>

typedef __bf16 bf16;
typedef __bf16 bf16x8 __attribute__((ext_vector_type(8)));
typedef __bf16 bf16x4 __attribute__((ext_vector_type(4)));
typedef float  f32x4  __attribute__((ext_vector_type(4)));
typedef float  f32x16 __attribute__((ext_vector_type(16)));
typedef unsigned int u32x4 __attribute__((ext_vector_type(4)));

#define MFMA16(a, b, c) __builtin_amdgcn_mfma_f32_16x16x32_bf16((a), (b), (c), 0, 0, 0)
#define MFMA32(a, b, c) __builtin_amdgcn_mfma_f32_32x32x16_bf16((a), (b), (c), 0, 0, 0)

// async global->LDS, 16B per lane, LDS dst = wave-uniform base + lane*16
__device__ __forceinline__ void gload_lds16(const bf16* g, bf16* l) {
  __builtin_amdgcn_global_load_lds(
      (const __attribute__((address_space(1))) void*)g,
      (__attribute__((address_space(3))) void*)l, 16, 0, 0);
}

// ---------------- prep kernels ----------------

__global__ __launch_bounds__(256) void cast_bf16_kernel(
    const float* __restrict__ in, bf16* __restrict__ out, int n4) {
  int i = blockIdx.x * 256 + threadIdx.x;
  if (i < n4) {
    float4 v = reinterpret_cast<const float4*>(in)[i];
    bf16x4 o;
    o[0] = (bf16)v.x; o[1] = (bf16)v.y; o[2] = (bf16)v.z; o[3] = (bf16)v.w;
    reinterpret_cast<bf16x4*>(out)[i] = o;
  }
}

__global__ __launch_bounds__(256) void transpose_cast_kernel(
    const float* __restrict__ W, bf16* __restrict__ Wt, int K, int N) {
  __shared__ bf16 tile[64 * 66];
  const int k0 = blockIdx.y * 64, n0 = blockIdx.x * 64;
  const int c = threadIdx.x & 63, rb = threadIdx.x >> 6;
#pragma unroll
  for (int p = 0; p < 16; ++p) {
    int r = p * 4 + rb;
    tile[c * 66 + r] = (bf16)W[(long)(k0 + r) * N + n0 + c];
  }
  __syncthreads();
#pragma unroll
  for (int p = 0; p < 16; ++p) {
    int r = p * 4 + rb;
    Wt[(long)(n0 + r) * K + k0 + c] = tile[r * 66 + c];
  }
}

// ---------------- GEMM: C(M,N) = A(M,K) @ Bt(N,K)^T, m97 structure ----------------
template <int EPI>
__global__ __launch_bounds__(256, 2) void gemm_bt(
    const bf16* __restrict__ A, const bf16* __restrict__ Bt,
    const float* __restrict__ bias, bf16* __restrict__ oQ,
    bf16* __restrict__ oK, bf16* __restrict__ oVT, float* __restrict__ oC,
    int K) {
  __shared__ bf16 As[128 * 64];
  __shared__ bf16 Bs[128 * 64];
  const int tid = threadIdx.x, lane = tid & 63, wid = tid >> 6;
  const int wr = wid >> 1, wc = wid & 1;
  const int brow = blockIdx.x * 128, bcol = blockIdx.y * 128;
  const int srow = lane >> 3, scol8 = (lane & 7) * 8;
  const int c15 = lane & 15, g = lane >> 4;

  f32x4 acc[4][4];
#pragma unroll
  for (int m = 0; m < 4; ++m)
#pragma unroll
    for (int n = 0; n < 4; ++n) acc[m][n] = f32x4{0.f, 0.f, 0.f, 0.f};

  const bf16* Ab = A + (long)brow * K + scol8;
  const bf16* Bb = Bt + (long)bcol * K + scol8;

  for (int k0 = 0; k0 < K; k0 += 64) {
#pragma unroll
    for (int i = 0; i < 4; ++i) {
      int c = wid * 4 + i;
      int row = c * 8 + srow;
      gload_lds16(Ab + (long)row * K + k0, &As[c * 512]);
    }
#pragma unroll
    for (int i = 0; i < 4; ++i) {
      int c = wid * 4 + i;
      int row = c * 8 + srow;
      gload_lds16(Bb + (long)row * K + k0, &Bs[c * 512]);
    }
    __syncthreads();
#pragma unroll
    for (int kk = 0; kk < 64; kk += 32) {
      bf16x8 a[4], b[4];
#pragma unroll
      for (int m = 0; m < 4; ++m)
        a[m] = *(const bf16x8*)&As[(wr * 64 + m * 16 + c15) * 64 + kk + g * 8];
#pragma unroll
      for (int n = 0; n < 4; ++n)
        b[n] = *(const bf16x8*)&Bs[(wc * 64 + n * 16 + c15) * 64 + kk + g * 8];
#pragma unroll
      for (int m = 0; m < 4; ++m)
#pragma unroll
        for (int n = 0; n < 4; ++n)
          acc[m][n] = MFMA16(a[m], b[n], acc[m][n]);
    }
    __syncthreads();
  }

#pragma unroll
  for (int n = 0; n < 4; ++n) {
    const int col = bcol + wc * 64 + n * 16 + c15;
    const float bv = bias[col];
    if (EPI == 0) {
      const int which = col >> 10, wi = col & 1023, h = wi >> 6, d = wi & 63;
      const float sc = (which == 0) ? 0.18033688011112042f : 1.0f;  // 0.125*log2(e)
#pragma unroll
      for (int m = 0; m < 4; ++m) {
        const int row0 = brow + wr * 64 + m * 16 + g * 4;
        const int bb = row0 >> 11, t0 = row0 & 2047;
        const long hb = bb * 16 + h;
        if (which == 2) {
          bf16x4 pv;
#pragma unroll
          for (int r = 0; r < 4; ++r) pv[r] = (bf16)(acc[m][n][r] + bv);
          *(bf16x4*)&oVT[(hb * 64 + d) * 2048 + t0] = pv;  // (b,h,d,t)
        } else {
          bf16* dst = ((which == 0) ? oQ : oK) + (hb * 2048 + t0) * 64 + d;
#pragma unroll
          for (int r = 0; r < 4; ++r)
            dst[(long)r * 64] = (bf16)((acc[m][n][r] + bv) * sc);
        }
      }
    } else {
#pragma unroll
      for (int m = 0; m < 4; ++m) {
        const long row = brow + wr * 64 + m * 16 + g * 4;
#pragma unroll
        for (int r = 0; r < 4; ++r) oC[(row + r) * 1024 + col] = acc[m][n][r] + bv;
      }
    }
  }
}

// ---------------- flash attention: LDS-staged K/V, cross-block KV-split x2 ---
// 1024 blocks (32 bh x 16 q-blocks x 2 splits) x 4 waves; all 4 waves share a
// staged 64-key K/V tile (coalesced global_load_lds, XOR-preswizzled source so
// ds_read_b128 fragments are ~4-way instead of 32-way conflicted); each wave
// owns 32 queries. Round-7 lesson: direct per-lane K/V loads were TA/L1
// transaction-bound (64 cache lines per load instr) -- staging coalesces them.
// Each block writes raw partial (O, m, l); merge kernel combines the 2 splits.
__global__ __launch_bounds__(256, 4) void attn_kernel(
    const bf16* __restrict__ Q, const bf16* __restrict__ K,
    const bf16* __restrict__ VT, const int* __restrict__ mask,
    float* __restrict__ O_part, float* __restrict__ ml_part) {
  __shared__ bf16 Kl[2][4096];  // [buf][64 keys x 64 kdim], 8-elem groups XOR-swizzled
  __shared__ bf16 Vl[2][4096];  // [buf][64 d x 64 keys], same swizzle
  __shared__ float sws[4][32];  // rare-path rescale broadcast
  const int tid = threadIdx.x, lane = tid & 63, w = tid >> 6;
  const int col = lane & 31, hi = lane >> 5, c7 = col & 7;
  const int bid = blockIdx.x;
  const int swz = (bid & 7) * 128 + (bid >> 3);  // XCD swizzle: 4 bh per XCD
  const int bh = swz >> 5, rem = swz & 31;
  const int s = rem & 1, qb = rem >> 1;
  const int b = bh >> 4, h = bh & 15;
  const int q0 = qb * 128 + w * 32;
  const int koff0 = s * 1024;

  const bf16* Kbase = K + (long)bh * 2048 * 64;
  const bf16* Vbase = VT + (long)bh * 64 * 2048;
  const int* mb = mask + b * 2048;

  // staging lane geometry: row = chunk*8 + (lane>>3); 8-elem group (lane&7),
  // source group pre-XORed with row&7 so linear LDS holds the swizzled layout
  const int srow = lane >> 3;
  const int xoff = ((lane & 7) ^ srow) << 3;

  auto stage = [&](int buf, int t) {
    const int koff = koff0 + t * 64;
#pragma unroll
    for (int i = 0; i < 2; ++i) {
      const int c = w * 2 + i;
      gload_lds16(Kbase + (long)(koff + c * 8 + srow) * 64 + xoff,
                  &Kl[buf][c * 512]);
      gload_lds16(Vbase + (long)(c * 8 + srow) * 2048 + koff + xoff,
                  &Vl[buf][c * 512]);
    }
  };

  // Q B-frag (pre-scaled by 0.125*log2e in gemm epilogue)
  const bf16* Qp = Q + ((long)bh * 2048 + q0 + col) * 64 + hi * 8;
  bf16x8 bq[4];
#pragma unroll
  for (int dc = 0; dc < 4; ++dc) bq[dc] = *(const bf16x8*)(Qp + dc * 16);

  f32x16 o0, o1;
#pragma unroll
  for (int r = 0; r < 16; ++r) { o0[r] = 0.f; o1[r] = 0.f; }
  float mrun = -1e30f, lrun = 0.f;  // lrun = per-half partial until fold

  stage(0, 0);
  for (int t = 0; t < 16; ++t) {
    const int cur = t & 1;
    __builtin_amdgcn_s_barrier();  // prev tile's LDS reads done before overwrite
    if (t < 15) {
      stage(cur ^ 1, t + 1);
      asm volatile("s_waitcnt vmcnt(4)" ::: "memory");  // tile t staged; t+1 in flight
    } else {
      asm volatile("s_waitcnt vmcnt(0)" ::: "memory");
    }
    __builtin_amdgcn_s_barrier();  // all waves' chunks of tile t visible

#pragma unroll
    for (int sub = 0; sub < 2; ++sub) {
      const int kk = koff0 + t * 64 + sub * 32;
      const int mv = mb[kk + col];
      // K A-frags from LDS (swizzled groups)
      const bf16* Krow = &Kl[cur][(sub * 32 + col) * 64];
      bf16x8 ak0 = *(const bf16x8*)(Krow + (((0 + hi) ^ c7) << 3));
      bf16x8 ak1 = *(const bf16x8*)(Krow + (((2 + hi) ^ c7) << 3));
      bf16x8 ak2 = *(const bf16x8*)(Krow + (((4 + hi) ^ c7) << 3));
      bf16x8 ak3 = *(const bf16x8*)(Krow + (((6 + hi) ^ c7) << 3));
      // S^T = K @ Q^T
      f32x16 st;
#pragma unroll
      for (int r = 0; r < 16; ++r) st[r] = 0.f;
      __builtin_amdgcn_s_setprio(1);
      st = MFMA32(ak0, bq[0], st);
      st = MFMA32(ak1, bq[1], st);
      st = MFMA32(ak2, bq[2], st);
      st = MFMA32(ak3, bq[3], st);
      __builtin_amdgcn_s_setprio(0);
      // mask (wave-uniform skip when all-ones)
      unsigned km32 = (unsigned)__ballot(mv != 0);
      if (km32 != 0xffffffffu) {
        unsigned km = km32 >> (hi * 4);
#pragma unroll
        for (int r = 0; r < 16; ++r)
          if (!((km >> ((r & 3) + 8 * (r >> 2))) & 1)) st[r] = -1e30f;
      }
      // per-half row max
      float m01 = fmaxf(st[0], st[1]), m23 = fmaxf(st[2], st[3]);
      float m45 = fmaxf(st[4], st[5]), m67 = fmaxf(st[6], st[7]);
      float m89 = fmaxf(st[8], st[9]), mab = fmaxf(st[10], st[11]);
      float mcd = fmaxf(st[12], st[13]), mef = fmaxf(st[14], st[15]);
      float m0 = fmaxf(fmaxf(fmaxf(m01, m23), fmaxf(m45, m67)),
                       fmaxf(fmaxf(m89, mab), fmaxf(mcd, mef)));
      // defer-max rescale (rare)
      if (__any(m0 > mrun + 8.0f)) {
        float pm = fmaxf(m0, __shfl_xor(m0, 32));
        float mnew = fmaxf(mrun, pm);
        float scale = __builtin_exp2f(mrun - mnew);
        mrun = mnew;
        lrun *= scale;
        if (hi == 0) sws[w][col] = scale;
        asm volatile("s_waitcnt lgkmcnt(0)" ::: "memory");
#pragma unroll
        for (int r = 0; r < 16; ++r) {
          float sc = sws[w][(r & 3) + 8 * (r >> 2) + 4 * hi];
          o0[r] *= sc; o1[r] *= sc;
        }
      }
      // P = exp2(S - m) in place; per-half row-sum into lrun
#pragma unroll
      for (int r = 0; r < 16; ++r) st[r] = __builtin_exp2f(st[r] - mrun);
      float s01 = st[0] + st[1], s23 = st[2] + st[3], s45 = st[4] + st[5];
      float s67 = st[6] + st[7], s89 = st[8] + st[9], sab = st[10] + st[11];
      float scd = st[12] + st[13], sef = st[14] + st[15];
      lrun += ((s01 + s23) + (s45 + s67)) + ((s89 + sab) + (scd + sef));
      // P -> bf16 A-frags; 4 cross-half exchanges in one window
      unsigned d0, d1, d2, d3, d4, d5, d6, d7;
      {
        union { bf16 hh[2]; unsigned u; } tt;
        tt.hh[0] = (bf16)st[0];  tt.hh[1] = (bf16)st[1];  d0 = tt.u;
        tt.hh[0] = (bf16)st[2];  tt.hh[1] = (bf16)st[3];  d1 = tt.u;
        tt.hh[0] = (bf16)st[4];  tt.hh[1] = (bf16)st[5];  d2 = tt.u;
        tt.hh[0] = (bf16)st[6];  tt.hh[1] = (bf16)st[7];  d3 = tt.u;
        tt.hh[0] = (bf16)st[8];  tt.hh[1] = (bf16)st[9];  d4 = tt.u;
        tt.hh[0] = (bf16)st[10]; tt.hh[1] = (bf16)st[11]; d5 = tt.u;
        tt.hh[0] = (bf16)st[12]; tt.hh[1] = (bf16)st[13]; d6 = tt.u;
        tt.hh[0] = (bf16)st[14]; tt.hh[1] = (bf16)st[15]; d7 = tt.u;
      }
      unsigned g02 = (unsigned)__shfl_xor((int)(hi ? d0 : d2), 32);
      unsigned g13 = (unsigned)__shfl_xor((int)(hi ? d1 : d3), 32);
      unsigned g46 = (unsigned)__shfl_xor((int)(hi ? d4 : d6), 32);
      unsigned g57 = (unsigned)__shfl_xor((int)(hi ? d5 : d7), 32);
      u32x4 w0 = {hi ? g02 : d0, hi ? g13 : d1, hi ? d2 : g02, hi ? d3 : g13};
      u32x4 w1 = {hi ? g46 : d4, hi ? g57 : d5, hi ? d6 : g46, hi ? d7 : g57};
      bf16x8 pa0 = __builtin_bit_cast(bf16x8, w0);
      bf16x8 pa1 = __builtin_bit_cast(bf16x8, w1);
      // V B-frags from LDS
      const bf16* Vrow0 = &Vl[cur][col * 64];
      const bf16* Vrow1 = &Vl[cur][(col + 32) * 64];
      const int g0 = ((sub * 4 + hi) ^ c7) << 3;
      const int g1 = ((sub * 4 + 2 + hi) ^ c7) << 3;
      bf16x8 bv00 = *(const bf16x8*)(Vrow0 + g0);
      bf16x8 bv10 = *(const bf16x8*)(Vrow0 + g1);
      bf16x8 bv01 = *(const bf16x8*)(Vrow1 + g0);
      bf16x8 bv11 = *(const bf16x8*)(Vrow1 + g1);
      // O += P @ V
      __builtin_amdgcn_s_setprio(1);
      o0 = MFMA32(pa0, bv00, o0);
      o0 = MFMA32(pa1, bv10, o0);
      o1 = MFMA32(pa0, bv01, o1);
      o1 = MFMA32(pa1, bv11, o1);
      __builtin_amdgcn_s_setprio(0);
    }
  }

  // ---- write raw partial (O, m, l) for cross-block merge ----
  lrun += __shfl_xor(lrun, 32);  // fold per-half l partials
  if (hi == 0) {
    float2 v; v.x = mrun; v.y = lrun;
    *(float2*)&ml_part[((long)s * 65536 + bh * 2048 + q0 + col) * 2] = v;
  }
  float* Os = O_part + (long)s * 4194304;
#pragma unroll
  for (int r = 0; r < 16; ++r) {
    const int qr = (r & 3) + 8 * (r >> 2) + 4 * hi;
    long base = ((long)b * 2048 + q0 + qr) * 1024 + h * 64 + col;
    Os[base] = o0[r];
    Os[base + 32] = o1[r];
  }
}

// ---------------- merge the 2 KV-split partials -> Aatt (bf16) ---------------
__global__ __launch_bounds__(256) void attn_merge_kernel(
    const float* __restrict__ O_part, const float* __restrict__ ml_part,
    bf16* __restrict__ Aout) {
  const int i = blockIdx.x * 256 + threadIdx.x;  // float4 group over 4096x1024
  const int qg = i >> 8;                         // global query row
  const int h = (i & 255) >> 4;
  const int bq = qg >> 11, t = qg & 2047;
  const int bh = bq * 16 + h;
  const float2 ml0 = *(const float2*)&ml_part[((long)bh * 2048 + t) * 2];
  const float2 ml1 = *(const float2*)&ml_part[((long)65536 + bh * 2048 + t) * 2];
  const float ms = fmaxf(ml0.x, ml1.x);
  const float w0 = __builtin_exp2f(ml0.x - ms);
  const float w1 = __builtin_exp2f(ml1.x - ms);
  const float inv = 1.0f / (w0 * ml0.y + w1 * ml1.y);
  float4 a = ((const float4*)O_part)[i];
  float4 c = ((const float4*)(O_part + 4194304))[i];
  bf16x4 o;
  o[0] = (bf16)((w0 * a.x + w1 * c.x) * inv);
  o[1] = (bf16)((w0 * a.y + w1 * c.y) * inv);
  o[2] = (bf16)((w0 * a.z + w1 * c.z) * inv);
  o[3] = (bf16)((w0 * a.w + w1 * c.w) * inv);
  ((bf16x4*)Aout)[i] = o;
}

// ---------------- launcher ----------------
extern "C" void kernel_launch(void* const* d_in, const int* in_sizes, int n_in,
                              void* d_out, int out_size, void* d_ws,
                              size_t ws_size, hipStream_t stream) {
  const float* x    = (const float*)d_in[0];
  const int*   mask = (const int*)d_in[1];
  const float* Wqkv = (const float*)d_in[2];
  const float* bqkv = (const float*)d_in[3];
  const float* Wout = (const float*)d_in[4];
  const float* bout = (const float*)d_in[5];
  float* out = (float*)d_out;

  char* ws = (char*)d_ws;
  bf16* xb    = (bf16*)(ws);                      // 8 MB; reused as Aatt
  bf16* wqkvT = (bf16*)(ws + (8u << 20));         // 6 MB
  bf16* woutT = (bf16*)(ws + (14u << 20));        // 2 MB
  bf16* Qb    = (bf16*)(ws + (16u << 20));        // 8 MB (b,h,t,d)
  bf16* Kb    = (bf16*)(ws + (24u << 20));        // 8 MB (b,h,t,d)
  bf16* VTb   = (bf16*)(ws + (32u << 20));        // 8 MB (b,h,d,t)
  float* Opart = (float*)(ws + (40u << 20));      // 32 MB (2 splits, fp32)
  float* mlp   = (float*)(ws + (72u << 20));      // 1 MB
  bf16* Aatt  = xb;

  cast_bf16_kernel<<<4096, 256, 0, stream>>>(x, xb, (4096 * 1024) / 4);
  transpose_cast_kernel<<<dim3(48, 16), 256, 0, stream>>>(Wqkv, wqkvT, 1024, 3072);
  transpose_cast_kernel<<<dim3(16, 16), 256, 0, stream>>>(Wout, woutT, 1024, 1024);
  gemm_bt<0><<<dim3(32, 24), 256, 0, stream>>>(xb, wqkvT, bqkv, Qb, Kb, VTb,
                                               nullptr, 1024);
  attn_kernel<<<1024, 256, 0, stream>>>(Qb, Kb, VTb, mask, Opart, mlp);
  attn_merge_kernel<<<4096, 256, 0, stream>>>(Opart, mlp, Aatt);
  gemm_bt<1><<<dim3(32, 8), 256, 0, stream>>>(Aatt, woutT, bout, nullptr,
                                              nullptr, nullptr, out, 1024);
}